// Round 1
// baseline (103.035 us; speedup 1.0000x reference)
//
#include <hip/hip_runtime.h>
#include <math.h>

// ---------------------------------------------------------------------------
// out[b] = <Z0> of: CNOT(1,0)·CNOT(0,1)·(Rot_l0 ⊗ Rot_l1) applied 3x to
//          (RX(x0)|0>) ⊗ (RX(x1)|0>).
// Collapsed to out = r^T K r, r = (c0c1, c0s1, s0c1, s0s1),
// K = Re(conj(phi_a) phi_b (M^† D M)_ab), phi=(1,-i,-i,-1), D=diag(1,1,-1,-1),
// M = product of the 3 fixed layer unitaries (weights-only -> prepass kernel).
// ---------------------------------------------------------------------------

struct c32 { float re, im; };
__device__ inline c32 cmul(c32 a, c32 b) { return { a.re*b.re - a.im*b.im, a.re*b.im + a.im*b.re }; }
__device__ inline c32 cadd(c32 a, c32 b) { return { a.re + b.re, a.im + b.im }; }
__device__ inline c32 cconj(c32 a) { return { a.re, -a.im }; }

__global__ void build_K(const float* __restrict__ w, float* __restrict__ K)
{
    if (threadIdx.x != 0 || blockIdx.x != 0) return;

    c32 M[4][4];
    #pragma unroll
    for (int i = 0; i < 4; ++i)
        for (int j = 0; j < 4; ++j)
            M[i][j] = { (i == j) ? 1.f : 0.f, 0.f };

    for (int l = 0; l < 3; ++l) {
        c32 U[2][2][2]; // [wire][row][col]
        for (int q = 0; q < 2; ++q) {
            float phi   = w[(l*2 + q)*3 + 0];
            float theta = w[(l*2 + q)*3 + 1];
            float omega = w[(l*2 + q)*3 + 2];
            float c = cosf(theta * 0.5f);
            float s = sinf(theta * 0.5f);
            float ap = -0.5f * (phi + omega);   // ep = exp(i*ap)
            float am =  0.5f * (phi - omega);   // em = exp(i*am)
            c32 ep = { cosf(ap), sinf(ap) };
            c32 em = { cosf(am), sinf(am) };
            U[q][0][0] = {  ep.re * c,  ep.im * c };
            U[q][0][1] = { -em.re * s, -em.im * s };
            U[q][1][0] = {  em.re * s, -em.im * s };  // conj(em)*s
            U[q][1][1] = {  ep.re * c, -ep.im * c };  // conj(ep)*c
        }
        // A = kron(U0, U1): A[2j+k][2j'+k'] = U0[j][j'] * U1[k][k']
        c32 A[4][4];
        for (int j = 0; j < 2; ++j)
            for (int k = 0; k < 2; ++k)
                for (int jp = 0; jp < 2; ++jp)
                    for (int kp = 0; kp < 2; ++kp)
                        A[2*j + k][2*jp + kp] = cmul(U[0][j][jp], U[1][k][kp]);
        // CNOT(ctrl=0,tgt=1): swap rows 2,3. CNOT(ctrl=1,tgt=0): swap rows 1,3.
        for (int col = 0; col < 4; ++col) { c32 t = A[2][col]; A[2][col] = A[3][col]; A[3][col] = t; }
        for (int col = 0; col < 4; ++col) { c32 t = A[1][col]; A[1][col] = A[3][col]; A[3][col] = t; }
        // M = A * M
        c32 NM[4][4];
        for (int i = 0; i < 4; ++i)
            for (int j = 0; j < 4; ++j) {
                c32 acc = {0.f, 0.f};
                for (int k = 0; k < 4; ++k) acc = cadd(acc, cmul(A[i][k], M[k][j]));
                NM[i][j] = acc;
            }
        for (int i = 0; i < 4; ++i)
            for (int j = 0; j < 4; ++j) M[i][j] = NM[i][j];
    }

    // H = M^dag D M, D = diag(1,1,-1,-1)
    const float Dv[4] = {1.f, 1.f, -1.f, -1.f};
    c32 H[4][4];
    for (int a = 0; a < 4; ++a)
        for (int b = 0; b < 4; ++b) {
            c32 acc = {0.f, 0.f};
            for (int c = 0; c < 4; ++c) {
                c32 t = cmul(cconj(M[c][a]), M[c][b]);
                acc.re += Dv[c] * t.re;
                acc.im += Dv[c] * t.im;
            }
            H[a][b] = acc;
        }

    // phi = (1, -i, -i, -1); K_ab = Re(conj(phi_a) * phi_b * H_ab)
    const c32 ph[4] = { {1.f,0.f}, {0.f,-1.f}, {0.f,-1.f}, {-1.f,0.f} };
    for (int a = 0; a < 4; ++a)
        for (int b = 0; b < 4; ++b) {
            c32 f = cmul(cconj(ph[a]), ph[b]);
            K[a*4 + b] = f.re * H[a][b].re - f.im * H[a][b].im;
        }
}

__global__ __launch_bounds__(256) void qexp_kernel(const float* __restrict__ x,
                                                   const float* __restrict__ K16,
                                                   float* __restrict__ out, int B)
{
    float K[16];
    #pragma unroll
    for (int i = 0; i < 16; ++i) K[i] = K16[i];   // uniform address -> scalar loads

    const long long t  = (long long)blockIdx.x * blockDim.x + threadIdx.x;
    const long long i0 = t * 4;
    if (i0 >= B) return;

    if (i0 + 4 <= B) {
        const float4* xp = (const float4*)(x + 2*i0);
        float4 a = xp[0], b = xp[1];
        float xs[8] = {a.x, a.y, a.z, a.w, b.x, b.y, b.z, b.w};
        float res[4];
        #pragma unroll
        for (int e = 0; e < 4; ++e) {
            float h0 = 0.5f * xs[2*e], h1 = 0.5f * xs[2*e + 1];
            float c0 = __cosf(h0), s0 = __sinf(h0);
            float c1 = __cosf(h1), s1 = __sinf(h1);
            float r[4] = {c0*c1, c0*s1, s0*c1, s0*s1};
            float acc = 0.f;
            #pragma unroll
            for (int ai = 0; ai < 4; ++ai) {
                float ta = 0.f;
                #pragma unroll
                for (int bi = 0; bi < 4; ++bi) ta += K[ai*4 + bi] * r[bi];
                acc += r[ai] * ta;
            }
            res[e] = acc;
        }
        *(float4*)(out + i0) = make_float4(res[0], res[1], res[2], res[3]);
    } else {
        for (long long i = i0; i < B; ++i) {
            float h0 = 0.5f * x[2*i], h1 = 0.5f * x[2*i + 1];
            float c0 = __cosf(h0), s0 = __sinf(h0);
            float c1 = __cosf(h1), s1 = __sinf(h1);
            float r[4] = {c0*c1, c0*s1, s0*c1, s0*s1};
            float acc = 0.f;
            for (int ai = 0; ai < 4; ++ai) {
                float ta = 0.f;
                for (int bi = 0; bi < 4; ++bi) ta += K[ai*4 + bi] * r[bi];
                acc += r[ai] * ta;
            }
            out[i] = acc;
        }
    }
}

extern "C" void kernel_launch(void* const* d_in, const int* in_sizes, int n_in,
                              void* d_out, int out_size, void* d_ws, size_t ws_size,
                              hipStream_t stream)
{
    const float* x = (const float*)d_in[0];      // [B, 2]
    const float* w = (const float*)d_in[1];      // [3, 2, 3]
    float* out = (float*)d_out;                  // [B]
    float* K   = (float*)d_ws;                   // 16 floats scratch

    const int B = in_sizes[0] / 2;

    build_K<<<1, 64, 0, stream>>>(w, K);

    const int elems_per_thread = 4;
    const long long n_threads = ((long long)B + elems_per_thread - 1) / elems_per_thread;
    const int block = 256;
    const int grid = (int)((n_threads + block - 1) / block);
    qexp_kernel<<<grid, block, 0, stream>>>(x, K, out, B);
}